// Round 1
// baseline (505.308 us; speedup 1.0000x reference)
//
#include <hip/hip_runtime.h>

// GAT layer, fp32. N=50000 nodes, E=800000 edges (+N self loops), DIN=256,
// DOUT=128, H=8 heads, DH=16.
//
// Pipeline (all on `stream`, graph-capture safe, ws re-derived every call):
//  K1 gemm_xwT    : h[N,128] = x[N,256] @ W_trans^T      (fp32, LDS-tiled)
//  K2 node_scores : a_src[v,h] = h[v,h,:]·Wa[:16], a_dst = ·Wa[16:32]
//  K3 init_count  : count[v] = 1  (self loop pre-counted)
//  K4 hist        : count[dst[e]]++ (int atomics)
//  K5 scan        : offsets = exclusive_scan(count); cursor = offsets
//  K6 scatter     : CSR by dst: src_sorted[atomicAdd(cursor[d])] = s
//  K7 aggregate   : one wave per dst node; out[v] = sum(e_k * h[src_k]) / sum(e_k)

constexpr int DIN  = 256;
constexpr int DOUT = 128;
constexpr int H    = 8;

__device__ __forceinline__ float lrelu(float s) { return s >= 0.0f ? s : 0.2f * s; }

// ---------------- K1: h = x @ W^T  (W is [DOUT, DIN] row-major) ----------------
__global__ __launch_bounds__(256) void gemm_xwT(const float* __restrict__ x,
                                                const float* __restrict__ W,
                                                float* __restrict__ h, int N) {
  constexpr int TM = 64, BK = 32;
  __shared__ __align__(16) float xs[BK][TM + 1];    // xs[k][row]; +1 pad -> conflict-free writes
  __shared__ __align__(16) float ws[BK][DOUT + 4];  // ws[k][o];  132 floats/row, 16B-aligned reads
  const int tid = threadIdx.x;
  const int rb  = blockIdx.x * TM;
  const int cx  = tid & 31;   // cols cx*4 .. cx*4+3
  const int ry  = tid >> 5;   // rows ry*8 .. ry*8+7

  float4 acc[8];
#pragma unroll
  for (int r = 0; r < 8; ++r) acc[r] = make_float4(0.f, 0.f, 0.f, 0.f);

  for (int k0 = 0; k0 < DIN; k0 += BK) {
    __syncthreads();
    // stage x tile 64x32, coalesced reads
#pragma unroll
    for (int i = 0; i < (TM * BK) / 256; ++i) {
      int li = i * 256 + tid;
      int row = li >> 5, col = li & 31;
      int gr = rb + row;
      xs[col][row] = (gr < N) ? x[(size_t)gr * DIN + k0 + col] : 0.f;
    }
    // stage W tile 128x32 (transposed), coalesced reads
#pragma unroll
    for (int i = 0; i < (DOUT * BK) / 256; ++i) {
      int li = i * 256 + tid;
      int o = li >> 5, col = li & 31;
      ws[col][o] = W[(size_t)o * DIN + k0 + col];
    }
    __syncthreads();
#pragma unroll
    for (int k = 0; k < BK; ++k) {
      float4 w4 = *(const float4*)&ws[k][cx * 4];
#pragma unroll
      for (int r = 0; r < 8; ++r) {
        float xv = xs[k][ry * 8 + r];
        acc[r].x += xv * w4.x; acc[r].y += xv * w4.y;
        acc[r].z += xv * w4.z; acc[r].w += xv * w4.w;
      }
    }
  }
#pragma unroll
  for (int r = 0; r < 8; ++r) {
    int row = rb + ry * 8 + r;
    if (row < N) *(float4*)&h[(size_t)row * DOUT + cx * 4] = acc[r];
  }
}

// ---------------- K2: per-node attention half-scores ----------------
__global__ __launch_bounds__(256) void node_scores(const float* __restrict__ h,
                                                   const float* __restrict__ Wa,
                                                   float* __restrict__ a_src,
                                                   float* __restrict__ a_dst, int N) {
  int idx = blockIdx.x * blockDim.x + threadIdx.x;
  if (idx >= N * H) return;
  int v = idx >> 3, hh = idx & 7;
  const float* hp = h + (size_t)v * DOUT + hh * 16;
  float s1 = 0.f, s2 = 0.f;
#pragma unroll
  for (int q = 0; q < 4; ++q) {
    float4 hv = *(const float4*)&hp[q * 4];
    float4 w1 = *(const float4*)&Wa[q * 4];
    float4 w2 = *(const float4*)&Wa[16 + q * 4];
    s1 += hv.x * w1.x + hv.y * w1.y + hv.z * w1.z + hv.w * w1.w;
    s2 += hv.x * w2.x + hv.y * w2.y + hv.z * w2.z + hv.w * w2.w;
  }
  a_src[idx] = s1;
  a_dst[idx] = s2;
}

// ---------------- K3/K4: histogram ----------------
__global__ void init_count(int* count, int N) {
  int i = blockIdx.x * blockDim.x + threadIdx.x;
  if (i < N) count[i] = 1;  // self loop
}

__global__ void hist(const int* __restrict__ ei, int* count, int E) {
  int e = blockIdx.x * blockDim.x + threadIdx.x;
  if (e < E) atomicAdd(&count[ei[E + e]], 1);
}

// ---------------- K5: single-block exclusive scan (N=50000) ----------------
__global__ __launch_bounds__(1024) void scan_kernel(const int* __restrict__ count,
                                                    int* __restrict__ offsets,
                                                    int* __restrict__ cursor, int n) {
  __shared__ int wave_sums[16];
  const int tid = threadIdx.x;
  const int CH = (n + 1023) / 1024;
  int begin = tid * CH;
  int end   = min(begin + CH, n);
  int sum = 0;
  for (int i = begin; i < end; ++i) sum += count[i];

  int lane = tid & 63, wid = tid >> 6;
  int v = sum;
#pragma unroll
  for (int d = 1; d < 64; d <<= 1) {
    int t = __shfl_up(v, d, 64);
    if (lane >= d) v += t;
  }
  if (lane == 63) wave_sums[wid] = v;
  __syncthreads();
  if (wid == 0) {
    int w = (lane < 16) ? wave_sums[lane] : 0;
#pragma unroll
    for (int d = 1; d < 16; d <<= 1) {
      int t = __shfl_up(w, d, 64);
      if (lane >= d) w += t;
    }
    if (lane < 16) wave_sums[lane] = w;
  }
  __syncthreads();
  int excl = v - sum + (wid > 0 ? wave_sums[wid - 1] : 0);
  int run = excl;
  for (int i = begin; i < end; ++i) {
    offsets[i] = run;
    cursor[i]  = run;
    run += count[i];
  }
  if (tid == 1023) offsets[n] = run;  // total = E + N
}

// ---------------- K6: scatter into CSR (grouped by dst) ----------------
__global__ void scatter(const int* __restrict__ ei, int* cursor,
                        int* __restrict__ src_sorted, int E, int N) {
  int i = blockIdx.x * blockDim.x + threadIdx.x;
  if (i >= E + N) return;
  int s, d;
  if (i < E) { s = ei[i]; d = ei[E + i]; }
  else       { s = i - E; d = s; }
  int pos = atomicAdd(&cursor[d], 1);
  src_sorted[pos] = s;
}

// ---------------- K7: per-node softmax-weighted aggregation ----------------
// One wave per dst node. Lane l owns out dims {2l, 2l+1}; head = l>>3.
__global__ __launch_bounds__(256) void aggregate(const float* __restrict__ h,
                                                 const float* __restrict__ a_src,
                                                 const float* __restrict__ a_dst,
                                                 const float* __restrict__ b_att,
                                                 const int* __restrict__ offsets,
                                                 const int* __restrict__ src_sorted,
                                                 float* __restrict__ out, int N) {
  int wid = blockIdx.x * (blockDim.x >> 6) + (threadIdx.x >> 6);
  if (wid >= N) return;
  int lane = threadIdx.x & 63;
  int head = lane >> 3;
  float adv = a_dst[wid * H + head] + b_att[0];
  int beg = offsets[wid], end = offsets[wid + 1];
  float ax = 0.f, ay = 0.f, den = 0.f;
  int j = beg;
  // 2-edge unroll: issue both gathers before consuming (hide L2/L3 latency)
  for (; j + 2 <= end; j += 2) {
    int s0 = src_sorted[j], s1 = src_sorted[j + 1];
    float as0 = a_src[s0 * H + head];
    float as1 = a_src[s1 * H + head];
    float2 h0 = *(const float2*)&h[(size_t)s0 * DOUT + lane * 2];
    float2 h1 = *(const float2*)&h[(size_t)s1 * DOUT + lane * 2];
    float e0 = __expf(lrelu(as0 + adv));
    float e1 = __expf(lrelu(as1 + adv));
    den += e0 + e1;
    ax += e0 * h0.x + e1 * h1.x;
    ay += e0 * h0.y + e1 * h1.y;
  }
  if (j < end) {
    int s0 = src_sorted[j];
    float as0 = a_src[s0 * H + head];
    float2 h0 = *(const float2*)&h[(size_t)s0 * DOUT + lane * 2];
    float e0 = __expf(lrelu(as0 + adv));
    den += e0; ax += e0 * h0.x; ay += e0 * h0.y;
  }
  float inv = 1.0f / den;
  float2 o; o.x = ax * inv; o.y = ay * inv;
  *(float2*)&out[(size_t)wid * DOUT + lane * 2] = o;
}

extern "C" void kernel_launch(void* const* d_in, const int* in_sizes, int n_in,
                              void* d_out, int out_size, void* d_ws, size_t ws_size,
                              hipStream_t stream) {
  const float* x     = (const float*)d_in[0];
  const float* W     = (const float*)d_in[1];
  const float* Wa    = (const float*)d_in[2];
  const float* b_att = (const float*)d_in[3];
  const int*   ei    = (const int*)d_in[4];
  const int N = in_sizes[0] / DIN;
  const int E = in_sizes[4] / 2;
  float* out = (float*)d_out;

  // workspace carve-up (16B-aligned fp32 blocks first, then ints) ~33 MB
  char* p = (char*)d_ws;
  float* h      = (float*)p; p += (size_t)N * DOUT * sizeof(float);
  float* a_src  = (float*)p; p += (size_t)N * H * sizeof(float);
  float* a_dst  = (float*)p; p += (size_t)N * H * sizeof(float);
  int* count    = (int*)p;   p += (size_t)N * sizeof(int);
  int* offsets  = (int*)p;   p += (size_t)(N + 1) * sizeof(int);
  int* cursor   = (int*)p;   p += (size_t)N * sizeof(int);
  int* src_sorted = (int*)p; p += (size_t)(E + N) * sizeof(int);

  dim3 b256(256);
  gemm_xwT<<<dim3((N + 63) / 64), b256, 0, stream>>>(x, W, h, N);
  node_scores<<<dim3((N * H + 255) / 256), b256, 0, stream>>>(h, Wa, a_src, a_dst, N);
  init_count<<<dim3((N + 255) / 256), b256, 0, stream>>>(count, N);
  hist<<<dim3((E + 255) / 256), b256, 0, stream>>>(ei, count, E);
  scan_kernel<<<dim3(1), dim3(1024), 0, stream>>>(count, offsets, cursor, N);
  scatter<<<dim3((E + N + 255) / 256), b256, 0, stream>>>(ei, cursor, src_sorted, E, N);
  aggregate<<<dim3((N + 3) / 4), b256, 0, stream>>>(h, a_src, a_dst, b_att, offsets,
                                                    src_sorted, out, N);
}

// Round 2
// 278.756 us; speedup vs baseline: 1.8127x; 1.8127x over previous
//
#include <hip/hip_runtime.h>

// GAT layer on MI355X. N=50000, E=800000 (+N self loops), DIN=256, DOUT=128, H=8.
//
//  K0 conv_w      : W_bf[128,256] = bf16(W_trans)
//  K1 gemm_mfma   : h_bf[N,128] = bf16( x @ W^T )   (16x16x32 bf16 MFMA, fp32 acc)
//  K2 node_scores : a_src[v,h] = h[v,h,:]·Wa[:16], a_dst = ·Wa[16:32]
//  K3 init_count  : count[v] = 1  (self loop)
//  K4 hist        : count[dst[e]]++
//  K5a/b/c scan   : offsets = exclusive_scan(count) (multi-block, 3 phases)
//  K6 scatter     : CSR by dst: src_sorted[atomicAdd(cursor[d])] = s
//  K7 aggregate   : one wave per dst node; out[v] = sum(e_k * h[src_k]) / sum(e_k)

constexpr int DIN  = 256;
constexpr int DOUT = 128;
constexpr int H    = 8;

typedef __attribute__((ext_vector_type(8))) short bf16x8;
typedef __attribute__((ext_vector_type(4))) float f32x4;

__device__ __forceinline__ float lrelu(float s) { return s >= 0.0f ? s : 0.2f * s; }

__device__ __forceinline__ short f2bf(float f) {  // RNE
  unsigned u = __float_as_uint(f);
  u += 0x7FFF + ((u >> 16) & 1);
  return (short)(u >> 16);
}
__device__ __forceinline__ float bflo(unsigned u) { return __uint_as_float(u << 16); }
__device__ __forceinline__ float bfhi(unsigned u) { return __uint_as_float(u & 0xFFFF0000u); }

// ---------------- K0: W -> bf16 ----------------
__global__ void conv_w(const float* __restrict__ W, short* __restrict__ Wbf, int n) {
  int i = blockIdx.x * blockDim.x + threadIdx.x;
  if (i < n) Wbf[i] = f2bf(W[i]);
}

// ---------------- K1: h_bf = bf16(x @ W^T), MFMA ----------------
// One wave per 16 rows; 8 n-tiles cover all 128 cols; K-loop 8 steps of 32.
// A-frag: lane holds A[m=lane&15][k = (lane>>4)*8 + j]   (x, converted in-flight)
// B-frag: lane holds B[k][n=lane&15], k = (lane>>4)*8+j  == W[n][k] (row-major slice)
// C/D   : col = lane&15, row = (lane>>4)*4 + reg
__global__ __launch_bounds__(256) void gemm_mfma(const float* __restrict__ x,
                                                 const short* __restrict__ Wbf,
                                                 unsigned short* __restrict__ hbf, int N) {
  int wid = blockIdx.x * 4 + (threadIdx.x >> 6);
  int m0 = wid * 16;
  if (m0 >= N) return;
  int lane = threadIdx.x & 63;
  int mr = lane & 15;
  int kg = lane >> 4;
  const float* xrow = x + (size_t)(m0 + mr) * DIN + kg * 8;

  f32x4 acc[8];
#pragma unroll
  for (int t = 0; t < 8; ++t) acc[t] = (f32x4){0.f, 0.f, 0.f, 0.f};

#pragma unroll
  for (int ks = 0; ks < 8; ++ks) {
    float4 alo = *(const float4*)(xrow + ks * 32);
    float4 ahi = *(const float4*)(xrow + ks * 32 + 4);
    bf16x8 a;
    a[0] = f2bf(alo.x); a[1] = f2bf(alo.y); a[2] = f2bf(alo.z); a[3] = f2bf(alo.w);
    a[4] = f2bf(ahi.x); a[5] = f2bf(ahi.y); a[6] = f2bf(ahi.z); a[7] = f2bf(ahi.w);
#pragma unroll
    for (int t = 0; t < 8; ++t) {
      bf16x8 b = *(const bf16x8*)(Wbf + ((size_t)(t * 16 + mr) * DIN + ks * 32 + kg * 8));
      acc[t] = __builtin_amdgcn_mfma_f32_16x16x32_bf16(a, b, acc[t], 0, 0, 0);
    }
  }
#pragma unroll
  for (int t = 0; t < 8; ++t) {
#pragma unroll
    for (int r = 0; r < 4; ++r) {
      int row = m0 + kg * 4 + r;
      hbf[(size_t)row * DOUT + t * 16 + mr] = (unsigned short)f2bf(acc[t][r]);
    }
  }
}

// ---------------- K2: per-node attention half-scores ----------------
__global__ __launch_bounds__(256) void node_scores(const unsigned short* __restrict__ hbf,
                                                   const float* __restrict__ Wa,
                                                   float* __restrict__ a_src,
                                                   float* __restrict__ a_dst, int N) {
  int idx = blockIdx.x * blockDim.x + threadIdx.x;
  if (idx >= N * H) return;
  int v = idx >> 3, hh = idx & 7;
  const unsigned short* hp = hbf + (size_t)v * DOUT + hh * 16;
  uint4 p0 = *(const uint4*)hp;
  uint4 p1 = *(const uint4*)(hp + 8);
  float hv[16];
  hv[0] = bflo(p0.x); hv[1] = bfhi(p0.x); hv[2] = bflo(p0.y); hv[3] = bfhi(p0.y);
  hv[4] = bflo(p0.z); hv[5] = bfhi(p0.z); hv[6] = bflo(p0.w); hv[7] = bfhi(p0.w);
  hv[8] = bflo(p1.x); hv[9] = bfhi(p1.x); hv[10] = bflo(p1.y); hv[11] = bfhi(p1.y);
  hv[12] = bflo(p1.z); hv[13] = bfhi(p1.z); hv[14] = bflo(p1.w); hv[15] = bfhi(p1.w);
  float s1 = 0.f, s2 = 0.f;
#pragma unroll
  for (int d = 0; d < 16; ++d) {
    s1 += hv[d] * Wa[d];
    s2 += hv[d] * Wa[16 + d];
  }
  a_src[idx] = s1;
  a_dst[idx] = s2;
}

// ---------------- K3/K4: histogram ----------------
__global__ void init_count(int* count, int N) {
  int i = blockIdx.x * blockDim.x + threadIdx.x;
  if (i < N) count[i] = 1;  // self loop
}

__global__ void hist(const int* __restrict__ ei, int* count, int E) {
  int e = blockIdx.x * blockDim.x + threadIdx.x;
  if (e < E) atomicAdd(&count[ei[E + e]], 1);
}

// ---------------- K5: 3-phase exclusive scan ----------------
__device__ __forceinline__ int wave_incl_scan(int v, int lane) {
#pragma unroll
  for (int d = 1; d < 64; d <<= 1) {
    int t = __shfl_up(v, d, 64);
    if (lane >= d) v += t;
  }
  return v;
}

__global__ __launch_bounds__(256) void scan_local(const int* __restrict__ count,
                                                  int* __restrict__ partial,
                                                  int* __restrict__ bsum, int n) {
  __shared__ int wsum[4];
  int i = blockIdx.x * 256 + threadIdx.x;
  int lane = threadIdx.x & 63, w = threadIdx.x >> 6;
  int v = (i < n) ? count[i] : 0;
  int inc = wave_incl_scan(v, lane);
  if (lane == 63) wsum[w] = inc;
  __syncthreads();
  int base = 0;
  for (int q = 0; q < w; ++q) base += wsum[q];
  if (i < n) partial[i] = base + inc - v;
  if (threadIdx.x == 255) bsum[blockIdx.x] = base + inc;
}

__global__ __launch_bounds__(256) void scan_blocks(const int* __restrict__ bsum,
                                                   int* __restrict__ bbase, int nb) {
  __shared__ int wsum[4];
  int lane = threadIdx.x & 63, w = threadIdx.x >> 6;
  int v = (threadIdx.x < nb) ? bsum[threadIdx.x] : 0;
  int inc = wave_incl_scan(v, lane);
  if (lane == 63) wsum[w] = inc;
  __syncthreads();
  int base = 0;
  for (int q = 0; q < w; ++q) base += wsum[q];
  if (threadIdx.x < nb) bbase[threadIdx.x] = base + inc - v;
}

__global__ void scan_add(const int* __restrict__ partial, const int* __restrict__ bbase,
                         int* __restrict__ offsets, int* __restrict__ cursor,
                         int n, int total) {
  int i = blockIdx.x * 256 + threadIdx.x;
  if (i < n) {
    int o = partial[i] + bbase[blockIdx.x];
    offsets[i] = o;
    cursor[i] = o;
  }
  if (i == 0) offsets[n] = total;
}

// ---------------- K6: scatter into CSR (grouped by dst) ----------------
__global__ void scatter(const int* __restrict__ ei, int* cursor,
                        int* __restrict__ src_sorted, int E, int N) {
  int i = blockIdx.x * blockDim.x + threadIdx.x;
  if (i >= E + N) return;
  int s, d;
  if (i < E) { s = ei[i]; d = ei[E + i]; }
  else       { s = i - E; d = s; }
  int pos = atomicAdd(&cursor[d], 1);
  src_sorted[pos] = s;
}

// ---------------- K7: per-node softmax-weighted aggregation ----------------
// One wave per dst node. Lane l owns out cols {2l, 2l+1}; head = l>>3.
// h_bf row = 256 B -> one wave-wide 4 B/lane gather per edge.
__global__ __launch_bounds__(256) void aggregate(const unsigned short* __restrict__ hbf,
                                                 const float* __restrict__ a_src,
                                                 const float* __restrict__ a_dst,
                                                 const float* __restrict__ b_att,
                                                 const int* __restrict__ offsets,
                                                 const int* __restrict__ src_sorted,
                                                 float* __restrict__ out, int N) {
  int wid = blockIdx.x * (blockDim.x >> 6) + (threadIdx.x >> 6);
  if (wid >= N) return;
  int lane = threadIdx.x & 63;
  int head = lane >> 3;
  float adv = a_dst[wid * H + head] + b_att[0];
  int beg = offsets[wid], end = offsets[wid + 1];
  float ax = 0.f, ay = 0.f, den = 0.f;
  int j = beg;
  for (; j + 4 <= end; j += 4) {  // 4-edge unroll: 4 independent gathers in flight
    int s0 = src_sorted[j], s1 = src_sorted[j + 1];
    int s2 = src_sorted[j + 2], s3 = src_sorted[j + 3];
    float as0 = a_src[s0 * H + head], as1 = a_src[s1 * H + head];
    float as2 = a_src[s2 * H + head], as3 = a_src[s3 * H + head];
    unsigned u0 = *(const unsigned*)(hbf + (size_t)s0 * DOUT + lane * 2);
    unsigned u1 = *(const unsigned*)(hbf + (size_t)s1 * DOUT + lane * 2);
    unsigned u2 = *(const unsigned*)(hbf + (size_t)s2 * DOUT + lane * 2);
    unsigned u3 = *(const unsigned*)(hbf + (size_t)s3 * DOUT + lane * 2);
    float e0 = __expf(lrelu(as0 + adv));
    float e1 = __expf(lrelu(as1 + adv));
    float e2 = __expf(lrelu(as2 + adv));
    float e3 = __expf(lrelu(as3 + adv));
    den += (e0 + e1) + (e2 + e3);
    ax += e0 * bflo(u0) + e1 * bflo(u1) + e2 * bflo(u2) + e3 * bflo(u3);
    ay += e0 * bfhi(u0) + e1 * bfhi(u1) + e2 * bfhi(u2) + e3 * bfhi(u3);
  }
  for (; j < end; ++j) {
    int s0 = src_sorted[j];
    float as0 = a_src[s0 * H + head];
    unsigned u0 = *(const unsigned*)(hbf + (size_t)s0 * DOUT + lane * 2);
    float e0 = __expf(lrelu(as0 + adv));
    den += e0; ax += e0 * bflo(u0); ay += e0 * bfhi(u0);
  }
  float inv = 1.0f / den;
  float2 o; o.x = ax * inv; o.y = ay * inv;
  *(float2*)&out[(size_t)wid * DOUT + lane * 2] = o;
}

extern "C" void kernel_launch(void* const* d_in, const int* in_sizes, int n_in,
                              void* d_out, int out_size, void* d_ws, size_t ws_size,
                              hipStream_t stream) {
  const float* x     = (const float*)d_in[0];
  const float* W     = (const float*)d_in[1];
  const float* Wa    = (const float*)d_in[2];
  const float* b_att = (const float*)d_in[3];
  const int*   ei    = (const int*)d_in[4];
  const int N = in_sizes[0] / DIN;
  const int E = in_sizes[4] / 2;
  const int nb = (N + 255) / 256;
  float* out = (float*)d_out;

  // workspace carve-up, 16B-aligned segments (~21 MB total)
  char* p = (char*)d_ws;
  auto take = [&p](size_t bytes) {
    uintptr_t u = ((uintptr_t)p + 15) & ~(uintptr_t)15;
    p = (char*)(u + bytes);
    return (void*)u;
  };
  unsigned short* hbf = (unsigned short*)take((size_t)N * DOUT * 2);
  short* Wbf          = (short*)take((size_t)DOUT * DIN * 2);
  float* a_src        = (float*)take((size_t)N * H * 4);
  float* a_dst        = (float*)take((size_t)N * H * 4);
  int* count          = (int*)take((size_t)N * 4);
  int* partial        = (int*)take((size_t)N * 4);
  int* offsets        = (int*)take((size_t)(N + 1) * 4);
  int* cursor         = (int*)take((size_t)N * 4);
  int* bsum           = (int*)take((size_t)nb * 4);
  int* bbase          = (int*)take((size_t)nb * 4);
  int* src_sorted     = (int*)take((size_t)(E + N) * 4);

  dim3 b256(256);
  conv_w<<<dim3((DOUT * DIN + 255) / 256), b256, 0, stream>>>(W, Wbf, DOUT * DIN);
  {
    int nwaves = (N + 15) / 16;
    gemm_mfma<<<dim3((nwaves + 3) / 4), b256, 0, stream>>>(x, Wbf, hbf, N);
  }
  node_scores<<<dim3((N * H + 255) / 256), b256, 0, stream>>>(hbf, Wa, a_src, a_dst, N);
  init_count<<<dim3(nb), b256, 0, stream>>>(count, N);
  hist<<<dim3((E + 255) / 256), b256, 0, stream>>>(ei, count, E);
  scan_local<<<dim3(nb), b256, 0, stream>>>(count, partial, bsum, N);
  scan_blocks<<<dim3(1), b256, 0, stream>>>(bsum, bbase, nb);
  scan_add<<<dim3(nb), b256, 0, stream>>>(partial, bbase, offsets, cursor, N, E + N);
  scatter<<<dim3((E + N + 255) / 256), b256, 0, stream>>>(ei, cursor, src_sorted, E, N);
  aggregate<<<dim3((N + 3) / 4), b256, 0, stream>>>(hbf, a_src, a_dst, b_att, offsets,
                                                    src_sorted, out, N);
}

// Round 3
// 217.860 us; speedup vs baseline: 2.3194x; 1.2795x over previous
//
#include <hip/hip_runtime.h>

// GAT layer on MI355X. N=50000, E=800000 (+N self loops), DIN=256, DOUT=128, H=8.
//
//  K0 conv_w      : W_bf = bf16(W_trans); also zeroes bucket counters
//  K1 gemm_mfma   : h_bf[N,128] = bf16( x @ W^T )   (16x16x32 bf16 MFMA, fp32 acc)
//  K2 node_scores : a_src[v,h] = h[v,h,:]·Wa[:16], a_dst = ·Wa[16:32]
//  K3 bhist       : per-bucket (256-node range) edge histogram, LDS-staged
//  K4 bscan       : exclusive scan over 196 buckets -> bbase, bcursor
//  K5 bucket_pass : partition (src,dst) pairs into bucket regions; per-block
//                   contiguous run reservation -> coalesced-ish writes
//  K6 fine_scatter: one block per bucket: per-dst LDS hist+scan -> offsets[],
//                   self-loop injection, rank-scatter into exclusive 17KB window
//  K7 aggregate   : one wave per dst node; out[v] = sum(e_k * h[src_k]) / sum(e_k)

constexpr int DIN  = 256;
constexpr int DOUT = 128;
constexpr int H    = 8;
constexpr int NPB  = 256;   // nodes per bucket (bucket id = dst >> 8)

typedef __attribute__((ext_vector_type(8))) short bf16x8;
typedef __attribute__((ext_vector_type(4))) float f32x4;

__device__ __forceinline__ float lrelu(float s) { return s >= 0.0f ? s : 0.2f * s; }

__device__ __forceinline__ short f2bf(float f) {  // RNE
  unsigned u = __float_as_uint(f);
  u += 0x7FFF + ((u >> 16) & 1);
  return (short)(u >> 16);
}
__device__ __forceinline__ float bflo(unsigned u) { return __uint_as_float(u << 16); }
__device__ __forceinline__ float bfhi(unsigned u) { return __uint_as_float(u & 0xFFFF0000u); }

__device__ __forceinline__ int wave_incl_scan(int v, int lane) {
#pragma unroll
  for (int d = 1; d < 64; d <<= 1) {
    int t = __shfl_up(v, d, 64);
    if (lane >= d) v += t;
  }
  return v;
}

// ---------------- K0: W -> bf16 (+ zero bucket counters) ----------------
__global__ void conv_w(const float* __restrict__ W, short* __restrict__ Wbf, int n,
                       int* __restrict__ bcount, int nb) {
  int i = blockIdx.x * blockDim.x + threadIdx.x;
  if (i < n) Wbf[i] = f2bf(W[i]);
  if (blockIdx.x == 0 && threadIdx.x < nb) bcount[threadIdx.x] = 0;
}

// ---------------- K1: h_bf = bf16(x @ W^T), MFMA ----------------
// A-frag: lane holds A[m=lane&15][k=(lane>>4)*8+j]; C/D: col=lane&15, row=(lane>>4)*4+reg
__global__ __launch_bounds__(256) void gemm_mfma(const float* __restrict__ x,
                                                 const short* __restrict__ Wbf,
                                                 unsigned short* __restrict__ hbf, int N) {
  int wid = blockIdx.x * 4 + (threadIdx.x >> 6);
  int m0 = wid * 16;
  if (m0 >= N) return;
  int lane = threadIdx.x & 63;
  int mr = lane & 15;
  int kg = lane >> 4;
  const float* xrow = x + (size_t)(m0 + mr) * DIN + kg * 8;

  f32x4 acc[8];
#pragma unroll
  for (int t = 0; t < 8; ++t) acc[t] = (f32x4){0.f, 0.f, 0.f, 0.f};

#pragma unroll
  for (int ks = 0; ks < 8; ++ks) {
    float4 alo = *(const float4*)(xrow + ks * 32);
    float4 ahi = *(const float4*)(xrow + ks * 32 + 4);
    bf16x8 a;
    a[0] = f2bf(alo.x); a[1] = f2bf(alo.y); a[2] = f2bf(alo.z); a[3] = f2bf(alo.w);
    a[4] = f2bf(ahi.x); a[5] = f2bf(ahi.y); a[6] = f2bf(ahi.z); a[7] = f2bf(ahi.w);
#pragma unroll
    for (int t = 0; t < 8; ++t) {
      bf16x8 b = *(const bf16x8*)(Wbf + ((size_t)(t * 16 + mr) * DIN + ks * 32 + kg * 8));
      acc[t] = __builtin_amdgcn_mfma_f32_16x16x32_bf16(a, b, acc[t], 0, 0, 0);
    }
  }
#pragma unroll
  for (int t = 0; t < 8; ++t) {
#pragma unroll
    for (int r = 0; r < 4; ++r) {
      int row = m0 + kg * 4 + r;
      hbf[(size_t)row * DOUT + t * 16 + mr] = (unsigned short)f2bf(acc[t][r]);
    }
  }
}

// ---------------- K2: per-node attention half-scores ----------------
__global__ __launch_bounds__(256) void node_scores(const unsigned short* __restrict__ hbf,
                                                   const float* __restrict__ Wa,
                                                   float* __restrict__ a_src,
                                                   float* __restrict__ a_dst, int N) {
  int idx = blockIdx.x * blockDim.x + threadIdx.x;
  if (idx >= N * H) return;
  int v = idx >> 3, hh = idx & 7;
  const unsigned short* hp = hbf + (size_t)v * DOUT + hh * 16;
  uint4 p0 = *(const uint4*)hp;
  uint4 p1 = *(const uint4*)(hp + 8);
  float hv[16];
  hv[0] = bflo(p0.x); hv[1] = bfhi(p0.x); hv[2] = bflo(p0.y); hv[3] = bfhi(p0.y);
  hv[4] = bflo(p0.z); hv[5] = bfhi(p0.z); hv[6] = bflo(p0.w); hv[7] = bfhi(p0.w);
  hv[8] = bflo(p1.x); hv[9] = bfhi(p1.x); hv[10] = bflo(p1.y); hv[11] = bfhi(p1.y);
  hv[12] = bflo(p1.z); hv[13] = bfhi(p1.z); hv[14] = bflo(p1.w); hv[15] = bfhi(p1.w);
  float s1 = 0.f, s2 = 0.f;
#pragma unroll
  for (int d = 0; d < 16; ++d) {
    s1 += hv[d] * Wa[d];
    s2 += hv[d] * Wa[16 + d];
  }
  a_src[idx] = s1;
  a_dst[idx] = s2;
}

// ---------------- K3: bucket histogram (LDS-staged) ----------------
__global__ __launch_bounds__(256) void bhist(const int* __restrict__ ei,
                                             int* __restrict__ bcount, int E, int nb) {
  __shared__ int h[256];
  h[threadIdx.x] = 0;
  __syncthreads();
  int stride = gridDim.x * 256;
  for (int e = blockIdx.x * 256 + threadIdx.x; e < E; e += stride)
    atomicAdd(&h[ei[E + e] >> 8], 1);
  __syncthreads();
  if (threadIdx.x < nb) {
    int c = h[threadIdx.x];
    if (c) atomicAdd(&bcount[threadIdx.x], c);
  }
}

// ---------------- K4: scan over buckets ----------------
__global__ __launch_bounds__(256) void bscan(const int* __restrict__ bcount,
                                             int* __restrict__ bbase,
                                             int* __restrict__ bcursor, int nb) {
  __shared__ int wsum[4];
  int t = threadIdx.x, lane = t & 63, w = t >> 6;
  int v = (t < nb) ? bcount[t] : 0;
  int inc = wave_incl_scan(v, lane);
  if (lane == 63) wsum[w] = inc;
  __syncthreads();
  int base = 0;
  for (int q = 0; q < w; ++q) base += wsum[q];
  int ex = base + inc - v;
  if (t < nb) { bbase[t] = ex; bcursor[t] = ex; }
  if (t == nb - 1) bbase[nb] = ex + v;  // == E
}

// ---------------- K5: partition pairs into bucket regions ----------------
constexpr int CHUNK = 4096;
__global__ __launch_bounds__(256) void bucket_pass(const int* __restrict__ ei,
                                                   int* __restrict__ bcursor,
                                                   int2* __restrict__ pair_buf,
                                                   int E, int nb) {
  __shared__ int hist[256];
  __shared__ int gbase[256];
  int c0 = blockIdx.x * CHUNK;
  hist[threadIdx.x] = 0;
  __syncthreads();
  for (int i = threadIdx.x; i < CHUNK; i += 256) {
    int e = c0 + i;
    if (e < E) atomicAdd(&hist[ei[E + e] >> 8], 1);
  }
  __syncthreads();
  if (threadIdx.x < nb) {
    int c = hist[threadIdx.x];
    gbase[threadIdx.x] = c ? atomicAdd(&bcursor[threadIdx.x], c) : 0;
  }
  __syncthreads();
  hist[threadIdx.x] = 0;  // reuse as local rank cursor
  __syncthreads();
  for (int i = threadIdx.x; i < CHUNK; i += 256) {
    int e = c0 + i;
    if (e < E) {
      int s = ei[e], d = ei[E + e];
      int b = d >> 8;
      int r = atomicAdd(&hist[b], 1);
      pair_buf[gbase[b] + r] = make_int2(s, d);
    }
  }
}

// ---------------- K6: per-bucket fine scatter + offsets + self loops ----------------
__global__ __launch_bounds__(256) void fine_scatter(const int2* __restrict__ pair_buf,
                                                    const int* __restrict__ bbase,
                                                    int* __restrict__ offsets,
                                                    int* __restrict__ src_sorted,
                                                    int N, int E, int nb) {
  __shared__ int cnt[256];
  __shared__ int cur[256];
  __shared__ int wsum[4];
  int b = blockIdx.x;
  int t = threadIdx.x, lane = t & 63, w = t >> 6;
  int node0 = b * NPB;
  int valid = (node0 + t < N);
  cnt[t] = valid ? 1 : 0;  // self loop
  __syncthreads();
  int seg0 = bbase[b], seg1 = bbase[b + 1];
  for (int i = seg0 + t; i < seg1; i += 256)
    atomicAdd(&cnt[pair_buf[i].y & 255], 1);
  __syncthreads();
  int v = cnt[t];
  int inc = wave_incl_scan(v, lane);
  if (lane == 63) wsum[w] = inc;
  __syncthreads();
  int base = 0;
  for (int q = 0; q < w; ++q) base += wsum[q];
  int ex = base + inc - v;
  cur[t] = ex + 1;  // slot 0 reserved for self loop
  int csr_base = seg0 + node0;  // edges before bucket + self loops before bucket
  if (valid) {
    offsets[node0 + t] = csr_base + ex;
    src_sorted[csr_base + ex] = node0 + t;  // self loop
  }
  if (b == nb - 1 && t == 0) offsets[N] = E + N;
  __syncthreads();
  for (int i = seg0 + t; i < seg1; i += 256) {
    int2 p = pair_buf[i];
    int r = atomicAdd(&cur[p.y & 255], 1);
    src_sorted[csr_base + r] = p.x;
  }
}

// ---------------- K7: per-node softmax-weighted aggregation ----------------
// One wave per dst node. Lane l owns out cols {2l, 2l+1}; head = l>>3.
__global__ __launch_bounds__(256) void aggregate(const unsigned short* __restrict__ hbf,
                                                 const float* __restrict__ a_src,
                                                 const float* __restrict__ a_dst,
                                                 const float* __restrict__ b_att,
                                                 const int* __restrict__ offsets,
                                                 const int* __restrict__ src_sorted,
                                                 float* __restrict__ out, int N) {
  int wid = blockIdx.x * (blockDim.x >> 6) + (threadIdx.x >> 6);
  if (wid >= N) return;
  int lane = threadIdx.x & 63;
  int head = lane >> 3;
  float adv = a_dst[wid * H + head] + b_att[0];
  int beg = offsets[wid], end = offsets[wid + 1];
  float ax = 0.f, ay = 0.f, den = 0.f;
  int j = beg;
  for (; j + 4 <= end; j += 4) {  // 4 independent gathers in flight
    int s0 = src_sorted[j], s1 = src_sorted[j + 1];
    int s2 = src_sorted[j + 2], s3 = src_sorted[j + 3];
    float as0 = a_src[s0 * H + head], as1 = a_src[s1 * H + head];
    float as2 = a_src[s2 * H + head], as3 = a_src[s3 * H + head];
    unsigned u0 = *(const unsigned*)(hbf + (size_t)s0 * DOUT + lane * 2);
    unsigned u1 = *(const unsigned*)(hbf + (size_t)s1 * DOUT + lane * 2);
    unsigned u2 = *(const unsigned*)(hbf + (size_t)s2 * DOUT + lane * 2);
    unsigned u3 = *(const unsigned*)(hbf + (size_t)s3 * DOUT + lane * 2);
    float e0 = __expf(lrelu(as0 + adv));
    float e1 = __expf(lrelu(as1 + adv));
    float e2 = __expf(lrelu(as2 + adv));
    float e3 = __expf(lrelu(as3 + adv));
    den += (e0 + e1) + (e2 + e3);
    ax += e0 * bflo(u0) + e1 * bflo(u1) + e2 * bflo(u2) + e3 * bflo(u3);
    ay += e0 * bfhi(u0) + e1 * bfhi(u1) + e2 * bfhi(u2) + e3 * bfhi(u3);
  }
  for (; j < end; ++j) {
    int s0 = src_sorted[j];
    float as0 = a_src[s0 * H + head];
    unsigned u0 = *(const unsigned*)(hbf + (size_t)s0 * DOUT + lane * 2);
    float e0 = __expf(lrelu(as0 + adv));
    den += e0; ax += e0 * bflo(u0); ay += e0 * bfhi(u0);
  }
  float inv = 1.0f / den;
  float2 o; o.x = ax * inv; o.y = ay * inv;
  *(float2*)&out[(size_t)wid * DOUT + lane * 2] = o;
}

extern "C" void kernel_launch(void* const* d_in, const int* in_sizes, int n_in,
                              void* d_out, int out_size, void* d_ws, size_t ws_size,
                              hipStream_t stream) {
  const float* x     = (const float*)d_in[0];
  const float* W     = (const float*)d_in[1];
  const float* Wa    = (const float*)d_in[2];
  const float* b_att = (const float*)d_in[3];
  const int*   ei    = (const int*)d_in[4];
  const int N  = in_sizes[0] / DIN;
  const int E  = in_sizes[4] / 2;
  const int NB = (N + NPB - 1) / NPB;  // 196
  float* out = (float*)d_out;

  // workspace carve-up, 16B-aligned segments (~25 MB total)
  char* p = (char*)d_ws;
  auto take = [&p](size_t bytes) {
    uintptr_t u = ((uintptr_t)p + 15) & ~(uintptr_t)15;
    p = (char*)(u + bytes);
    return (void*)u;
  };
  unsigned short* hbf = (unsigned short*)take((size_t)N * DOUT * 2);
  short* Wbf          = (short*)take((size_t)DOUT * DIN * 2);
  float* a_src        = (float*)take((size_t)N * H * 4);
  float* a_dst        = (float*)take((size_t)N * H * 4);
  int* bcount         = (int*)take((size_t)NB * 4);
  int* bbase          = (int*)take((size_t)(NB + 1) * 4);
  int* bcursor        = (int*)take((size_t)NB * 4);
  int2* pair_buf      = (int2*)take((size_t)E * 8);
  int* offsets        = (int*)take((size_t)(N + 1) * 4);
  int* src_sorted     = (int*)take((size_t)(E + N) * 4);

  dim3 b256(256);
  conv_w<<<dim3((DOUT * DIN + 255) / 256), b256, 0, stream>>>(W, Wbf, DOUT * DIN, bcount, NB);
  {
    int nwaves = (N + 15) / 16;
    gemm_mfma<<<dim3((nwaves + 3) / 4), b256, 0, stream>>>(x, Wbf, hbf, N);
  }
  node_scores<<<dim3((N * H + 255) / 256), b256, 0, stream>>>(hbf, Wa, a_src, a_dst, N);
  bhist<<<dim3(256), b256, 0, stream>>>(ei, bcount, E, NB);
  bscan<<<dim3(1), b256, 0, stream>>>(bcount, bbase, bcursor, NB);
  bucket_pass<<<dim3((E + CHUNK - 1) / CHUNK), b256, 0, stream>>>(ei, bcursor, pair_buf, E, NB);
  fine_scatter<<<dim3(NB), b256, 0, stream>>>(pair_buf, bbase, offsets, src_sorted, N, E, NB);
  aggregate<<<dim3((N + 3) / 4), b256, 0, stream>>>(hbf, a_src, a_dst, b_att, offsets,
                                                    src_sorted, out, N);
}

// Round 4
// 201.771 us; speedup vs baseline: 2.5044x; 1.0797x over previous
//
#include <hip/hip_runtime.h>

// GAT layer on MI355X. N=50000, E=800000 (+N self loops), DIN=256, DOUT=128, H=8.
//
//  K1 conv_w       : W_bf = bf16(W_trans); zeroes bucket counters
//  K2 gemm_bhist   : [blocks 0..781]  h_bf = bf16(x @ W^T)  (16x16x32 bf16 MFMA)
//                    [blocks 782..]   per-bucket (dst>>8) edge histogram
//  K3 ns_bscan     : [blocks 0..1562] a_src/a_dst per-node attention half-scores
//                    [block 1563]     exclusive scan over 196 buckets
//  K4 bucket_pass  : partition edges into bucket regions; packed u32 (s<<8 | d&255)
//  K5 fine_scatter : one block per bucket: per-dst LDS hist+scan -> offsets[],
//                    self-loop injection, rank-scatter (ushort src ids)
//  K6 aggregate    : one wave per dst node, 2 edges per instruction
//                    (32-lane halves), out[v] = sum(e_k * h[src_k]) / sum(e_k)

constexpr int DIN  = 256;
constexpr int DOUT = 128;
constexpr int H    = 8;
constexpr int NPB  = 256;   // nodes per bucket (bucket id = dst >> 8)

typedef __attribute__((ext_vector_type(8))) short bf16x8;
typedef __attribute__((ext_vector_type(4))) float f32x4;

__device__ __forceinline__ float lrelu(float s) { return s >= 0.0f ? s : 0.2f * s; }

__device__ __forceinline__ short f2bf(float f) {  // RNE
  unsigned u = __float_as_uint(f);
  u += 0x7FFF + ((u >> 16) & 1);
  return (short)(u >> 16);
}
__device__ __forceinline__ float bflo(unsigned u) { return __uint_as_float(u << 16); }
__device__ __forceinline__ float bfhi(unsigned u) { return __uint_as_float(u & 0xFFFF0000u); }

__device__ __forceinline__ int wave_incl_scan(int v, int lane) {
#pragma unroll
  for (int d = 1; d < 64; d <<= 1) {
    int t = __shfl_up(v, d, 64);
    if (lane >= d) v += t;
  }
  return v;
}

// ---------------- K1: W -> bf16 (+ zero bucket counters) ----------------
__global__ void conv_w(const float* __restrict__ W, short* __restrict__ Wbf, int n,
                       int* __restrict__ bcount, int nb) {
  int i = blockIdx.x * blockDim.x + threadIdx.x;
  if (i < n) Wbf[i] = f2bf(W[i]);
  if (blockIdx.x == 0 && threadIdx.x < nb) bcount[threadIdx.x] = 0;
}

// ---------------- K2: fused GEMM (MFMA) + bucket histogram ----------------
// gemm: A-frag lane holds A[m=lane&15][k=(lane>>4)*8+j]; C/D: col=lane&15, row=(lane>>4)*4+reg
__global__ __launch_bounds__(256) void gemm_bhist(const float* __restrict__ x,
                                                  const short* __restrict__ Wbf,
                                                  unsigned short* __restrict__ hbf, int N,
                                                  const int* __restrict__ ei,
                                                  int* __restrict__ bcount, int E, int nb,
                                                  int gemm_blocks, int hist_blocks) {
  __shared__ int hsh[256];
  if ((int)blockIdx.x >= gemm_blocks) {
    // ---- bucket histogram ----
    int bb = blockIdx.x - gemm_blocks;
    hsh[threadIdx.x] = 0;
    __syncthreads();
    int stride = hist_blocks * 256;
    for (int e = bb * 256 + threadIdx.x; e < E; e += stride)
      atomicAdd(&hsh[ei[E + e] >> 8], 1);
    __syncthreads();
    if (threadIdx.x < nb) {
      int c = hsh[threadIdx.x];
      if (c) atomicAdd(&bcount[threadIdx.x], c);
    }
    return;
  }
  // ---- GEMM ----
  int wid = blockIdx.x * 4 + (threadIdx.x >> 6);
  int m0 = wid * 16;
  if (m0 >= N) return;
  int lane = threadIdx.x & 63;
  int mr = lane & 15;
  int kg = lane >> 4;
  const float* xrow = x + (size_t)(m0 + mr) * DIN + kg * 8;

  f32x4 acc[8];
#pragma unroll
  for (int t = 0; t < 8; ++t) acc[t] = (f32x4){0.f, 0.f, 0.f, 0.f};

#pragma unroll
  for (int ks = 0; ks < 8; ++ks) {
    float4 alo = *(const float4*)(xrow + ks * 32);
    float4 ahi = *(const float4*)(xrow + ks * 32 + 4);
    bf16x8 a;
    a[0] = f2bf(alo.x); a[1] = f2bf(alo.y); a[2] = f2bf(alo.z); a[3] = f2bf(alo.w);
    a[4] = f2bf(ahi.x); a[5] = f2bf(ahi.y); a[6] = f2bf(ahi.z); a[7] = f2bf(ahi.w);
#pragma unroll
    for (int t = 0; t < 8; ++t) {
      bf16x8 b = *(const bf16x8*)(Wbf + ((size_t)(t * 16 + mr) * DIN + ks * 32 + kg * 8));
      acc[t] = __builtin_amdgcn_mfma_f32_16x16x32_bf16(a, b, acc[t], 0, 0, 0);
    }
  }
#pragma unroll
  for (int t = 0; t < 8; ++t) {
#pragma unroll
    for (int r = 0; r < 4; ++r) {
      int row = m0 + kg * 4 + r;
      hbf[(size_t)row * DOUT + t * 16 + mr] = (unsigned short)f2bf(acc[t][r]);
    }
  }
}

// ---------------- K3: fused node scores + bucket scan ----------------
__global__ __launch_bounds__(256) void ns_bscan(const unsigned short* __restrict__ hbf,
                                                const float* __restrict__ Wa,
                                                float* __restrict__ a_src,
                                                float* __restrict__ a_dst, int N,
                                                const int* __restrict__ bcount,
                                                int* __restrict__ bbase,
                                                int* __restrict__ bcursor, int nb,
                                                int ns_blocks) {
  __shared__ int wsum[4];
  if ((int)blockIdx.x >= ns_blocks) {
    // ---- bucket scan ----
    int t = threadIdx.x, lane = t & 63, w = t >> 6;
    int v = (t < nb) ? bcount[t] : 0;
    int inc = wave_incl_scan(v, lane);
    if (lane == 63) wsum[w] = inc;
    __syncthreads();
    int base = 0;
    for (int q = 0; q < w; ++q) base += wsum[q];
    int ex = base + inc - v;
    if (t < nb) { bbase[t] = ex; bcursor[t] = ex; }
    if (t == nb - 1) bbase[nb] = ex + v;  // == E
    return;
  }
  int idx = blockIdx.x * blockDim.x + threadIdx.x;
  if (idx >= N * H) return;
  int v = idx >> 3, hh = idx & 7;
  const unsigned short* hp = hbf + (size_t)v * DOUT + hh * 16;
  uint4 p0 = *(const uint4*)hp;
  uint4 p1 = *(const uint4*)(hp + 8);
  float hv[16];
  hv[0] = bflo(p0.x); hv[1] = bfhi(p0.x); hv[2] = bflo(p0.y); hv[3] = bfhi(p0.y);
  hv[4] = bflo(p0.z); hv[5] = bfhi(p0.z); hv[6] = bflo(p0.w); hv[7] = bfhi(p0.w);
  hv[8] = bflo(p1.x); hv[9] = bfhi(p1.x); hv[10] = bflo(p1.y); hv[11] = bfhi(p1.y);
  hv[12] = bflo(p1.z); hv[13] = bfhi(p1.z); hv[14] = bflo(p1.w); hv[15] = bfhi(p1.w);
  float s1 = 0.f, s2 = 0.f;
#pragma unroll
  for (int d = 0; d < 16; ++d) {
    s1 += hv[d] * Wa[d];
    s2 += hv[d] * Wa[16 + d];
  }
  a_src[idx] = s1;
  a_dst[idx] = s2;
}

// ---------------- K4: partition edges into bucket regions (packed u32) ----------------
constexpr int CHUNK = 4096;  // 16 edges per thread
__global__ __launch_bounds__(256) void bucket_pass(const int* __restrict__ ei,
                                                   int* __restrict__ bcursor,
                                                   unsigned* __restrict__ pair_buf,
                                                   int E, int nb) {
  __shared__ int hist[256];
  __shared__ int gbase[256];
  int c0 = blockIdx.x * CHUNK;
  hist[threadIdx.x] = 0;
  __syncthreads();
  int dcache[16];
#pragma unroll
  for (int q = 0; q < 16; ++q) {
    int e = c0 + q * 256 + threadIdx.x;
    dcache[q] = (e < E) ? ei[E + e] : -1;
    if (dcache[q] >= 0) atomicAdd(&hist[dcache[q] >> 8], 1);
  }
  __syncthreads();
  if (threadIdx.x < nb) {
    int c = hist[threadIdx.x];
    gbase[threadIdx.x] = c ? atomicAdd(&bcursor[threadIdx.x], c) : 0;
  }
  __syncthreads();
  hist[threadIdx.x] = 0;  // reuse as local rank cursor
  __syncthreads();
#pragma unroll
  for (int q = 0; q < 16; ++q) {
    int e = c0 + q * 256 + threadIdx.x;
    if (dcache[q] >= 0) {
      int s = ei[e];
      int b = dcache[q] >> 8;
      int r = atomicAdd(&hist[b], 1);
      pair_buf[gbase[b] + r] = ((unsigned)s << 8) | (unsigned)(dcache[q] & 255);
    }
  }
}

// ---------------- K5: per-bucket fine scatter + offsets + self loops ----------------
__global__ __launch_bounds__(256) void fine_scatter(const unsigned* __restrict__ pair_buf,
                                                    const int* __restrict__ bbase,
                                                    int* __restrict__ offsets,
                                                    unsigned short* __restrict__ src_sorted,
                                                    int N, int E, int nb) {
  __shared__ int cnt[256];
  __shared__ int cur[256];
  __shared__ int wsum[4];
  int b = blockIdx.x;
  int t = threadIdx.x, lane = t & 63, w = t >> 6;
  int node0 = b * NPB;
  int valid = (node0 + t < N);
  cnt[t] = valid ? 1 : 0;  // self loop
  __syncthreads();
  int seg0 = bbase[b], seg1 = bbase[b + 1];
  for (int i = seg0 + t; i < seg1; i += 256)
    atomicAdd(&cnt[pair_buf[i] & 255], 1);
  __syncthreads();
  int v = cnt[t];
  int inc = wave_incl_scan(v, lane);
  if (lane == 63) wsum[w] = inc;
  __syncthreads();
  int base = 0;
  for (int q = 0; q < w; ++q) base += wsum[q];
  int ex = base + inc - v;
  cur[t] = ex + 1;  // slot 0 reserved for self loop
  int csr_base = seg0 + node0;  // edges before bucket + self loops before bucket
  if (valid) {
    offsets[node0 + t] = csr_base + ex;
    src_sorted[csr_base + ex] = (unsigned short)(node0 + t);  // self loop
  }
  if (b == nb - 1 && t == 0) offsets[N] = E + N;
  __syncthreads();
  for (int i = seg0 + t; i < seg1; i += 256) {
    unsigned p = pair_buf[i];
    int r = atomicAdd(&cur[p & 255], 1);
    src_sorted[csr_base + r] = (unsigned short)(p >> 8);
  }
}

// ---------------- K6: softmax-weighted aggregation, 2 edges / wave-instr ----------------
// One wave per dst node. Lanes [0,32) process edge j, [32,64) edge j+1.
// Sub-lane sl covers cols [sl*4, sl*4+4) (8B bf16 load); head = sl>>2.
__global__ __launch_bounds__(256) void aggregate(const unsigned short* __restrict__ hbf,
                                                 const float* __restrict__ a_src,
                                                 const float* __restrict__ a_dst,
                                                 const float* __restrict__ b_att,
                                                 const int* __restrict__ offsets,
                                                 const unsigned short* __restrict__ src_sorted,
                                                 float* __restrict__ out, int N) {
  int wid = blockIdx.x * 4 + (threadIdx.x >> 6);
  if (wid >= N) return;
  int lane = threadIdx.x & 63;
  int sub = lane >> 5;
  int sl = lane & 31;
  int head = sl >> 2;
  float adv = a_dst[wid * H + head] + b_att[0];
  int beg = offsets[wid], end = offsets[wid + 1];
  float ax = 0.f, ay = 0.f, az = 0.f, aw = 0.f, den = 0.f;
  int j = beg;
  for (; j + 4 <= end; j += 4) {  // 4 edges: 2 pairs, 2 independent gathers in flight
    int s0 = src_sorted[j + sub];
    int s1 = src_sorted[j + 2 + sub];
    float as0 = a_src[s0 * H + head];
    float as1 = a_src[s1 * H + head];
    uint2 u0 = *(const uint2*)(hbf + s0 * DOUT + sl * 4);
    uint2 u1 = *(const uint2*)(hbf + s1 * DOUT + sl * 4);
    float e0 = __expf(lrelu(as0 + adv));
    float e1 = __expf(lrelu(as1 + adv));
    den += e0 + e1;
    ax += e0 * bflo(u0.x) + e1 * bflo(u1.x);
    ay += e0 * bfhi(u0.x) + e1 * bfhi(u1.x);
    az += e0 * bflo(u0.y) + e1 * bflo(u1.y);
    aw += e0 * bfhi(u0.y) + e1 * bfhi(u1.y);
  }
  for (; j + 2 <= end; j += 2) {
    int s0 = src_sorted[j + sub];
    float as0 = a_src[s0 * H + head];
    uint2 u0 = *(const uint2*)(hbf + s0 * DOUT + sl * 4);
    float e0 = __expf(lrelu(as0 + adv));
    den += e0;
    ax += e0 * bflo(u0.x); ay += e0 * bfhi(u0.x);
    az += e0 * bflo(u0.y); aw += e0 * bfhi(u0.y);
  }
  if (j < end) {  // final odd edge: only sub==0 contributes
    int s0 = src_sorted[j];
    float as0 = a_src[s0 * H + head];
    uint2 u0 = *(const uint2*)(hbf + s0 * DOUT + sl * 4);
    float e0 = (sub == 0) ? __expf(lrelu(as0 + adv)) : 0.f;
    den += e0;
    ax += e0 * bflo(u0.x); ay += e0 * bfhi(u0.x);
    az += e0 * bflo(u0.y); aw += e0 * bfhi(u0.y);
  }
  // combine halves (lane ^ 32 holds the same cols for the other edge set)
  den += __shfl_xor(den, 32, 64);
  ax  += __shfl_xor(ax, 32, 64);
  ay  += __shfl_xor(ay, 32, 64);
  az  += __shfl_xor(az, 32, 64);
  aw  += __shfl_xor(aw, 32, 64);
  if (sub == 0) {
    float inv = 1.0f / den;
    float4 o = make_float4(ax * inv, ay * inv, az * inv, aw * inv);
    *(float4*)&out[wid * DOUT + sl * 4] = o;
  }
}

extern "C" void kernel_launch(void* const* d_in, const int* in_sizes, int n_in,
                              void* d_out, int out_size, void* d_ws, size_t ws_size,
                              hipStream_t stream) {
  const float* x     = (const float*)d_in[0];
  const float* W     = (const float*)d_in[1];
  const float* Wa    = (const float*)d_in[2];
  const float* b_att = (const float*)d_in[3];
  const int*   ei    = (const int*)d_in[4];
  const int N  = in_sizes[0] / DIN;
  const int E  = in_sizes[4] / 2;
  const int NB = (N + NPB - 1) / NPB;  // 196
  float* out = (float*)d_out;

  // workspace carve-up, 16B-aligned segments (~20 MB total)
  char* p = (char*)d_ws;
  auto take = [&p](size_t bytes) {
    uintptr_t u = ((uintptr_t)p + 15) & ~(uintptr_t)15;
    p = (char*)(u + bytes);
    return (void*)u;
  };
  unsigned short* hbf = (unsigned short*)take((size_t)N * DOUT * 2);
  short* Wbf          = (short*)take((size_t)DOUT * DIN * 2);
  float* a_src        = (float*)take((size_t)N * H * 4);
  float* a_dst        = (float*)take((size_t)N * H * 4);
  int* bcount         = (int*)take((size_t)NB * 4);
  int* bbase          = (int*)take((size_t)(NB + 1) * 4);
  int* bcursor        = (int*)take((size_t)NB * 4);
  unsigned* pair_buf  = (unsigned*)take((size_t)E * 4);
  int* offsets        = (int*)take((size_t)(N + 1) * 4);
  unsigned short* src_sorted = (unsigned short*)take((size_t)(E + N) * 2);

  dim3 b256(256);
  const int gemm_blocks = ((N + 15) / 16 + 3) / 4;  // 782
  const int hist_blocks = 256;
  const int ns_blocks = (N * H + 255) / 256;        // 1563

  conv_w<<<dim3((DOUT * DIN + 255) / 256), b256, 0, stream>>>(W, Wbf, DOUT * DIN, bcount, NB);
  gemm_bhist<<<dim3(gemm_blocks + hist_blocks), b256, 0, stream>>>(
      x, Wbf, hbf, N, ei, bcount, E, NB, gemm_blocks, hist_blocks);
  ns_bscan<<<dim3(ns_blocks + 1), b256, 0, stream>>>(hbf, Wa, a_src, a_dst, N,
                                                     bcount, bbase, bcursor, NB, ns_blocks);
  bucket_pass<<<dim3((E + CHUNK - 1) / CHUNK), b256, 0, stream>>>(ei, bcursor, pair_buf, E, NB);
  fine_scatter<<<dim3(NB), b256, 0, stream>>>(pair_buf, bbase, offsets, src_sorted, N, E, NB);
  aggregate<<<dim3((N + 3) / 4), b256, 0, stream>>>(hbf, a_src, a_dst, b_att, offsets,
                                                    src_sorted, out, N);
}